// Round 10
// baseline (1062.500 us; speedup 1.0000x reference)
//
#include <hip/hip_runtime.h>
#include <cstddef>
#include <cstdint>

#define NB 8
#define NPTS 4096
#define NS 1024
#define NK 32
#define ND 64

typedef __attribute__((ext_vector_type(8))) short bf16x8;  // 8 bf16 (4 VGPRs)
typedef __attribute__((ext_vector_type(4))) float f32x4;

__device__ __forceinline__ short f2bf(float f) {  // RNE f32->bf16
  unsigned u = __float_as_uint(f);
  u += 0x7FFF + ((u >> 16) & 1);
  return (short)(u >> 16);
}

__device__ __forceinline__ float bf2f(unsigned short u) {
  return __uint_as_float((unsigned)u << 16);
}

// ------------------------------------------------------------------
// R22: producer-consumer pipeline. One cooperative kernel, 256 blocks
// x 512 threads, static LDS 82KB (>80KB -> 1 block/CU: fps blocks own
// their CU, no spin roommates; cooperative launch guarantees all 256
// co-resident -> no dispatch-order deadlock, G16-safe).
//  blocks 0-7:  fps (R15 chain verbatim) + chunked publication: every
//               64 steps wave0 writes 64 centroids to ws_newxyz and
//               release-stores prog[b] (agent scope).
//  blocks 8+:   pgemm tiles (release-counted into pdone), then query
//               pairs: acquire-poll prog[b] > s with s_sleep backoff;
//               query math = R21 verbatim; partials per-pair (stats0
//               nblocks 8192, double-accum makes order change benign).
// prog/pdone zeroed by stream-ordered hipMemsetAsync (replay-safe).
// ------------------------------------------------------------------
#define DPP_IMAX(v, ctrl)                                                     \
  {                                                                           \
    int _o = __builtin_amdgcn_update_dpp(v, v, ctrl, 0xf, 0xf, false);        \
    v = (_o > v) ? _o : v;                                                    \
  }

#define DPP_U64MAX(hi, lo, ctrl)                                              \
  {                                                                           \
    unsigned _nh = (unsigned)__builtin_amdgcn_update_dpp((int)(hi), (int)(hi),\
                                                         ctrl, 0xf, 0xf, false);\
    unsigned _nl = (unsigned)__builtin_amdgcn_update_dpp((int)(lo), (int)(lo),\
                                                         ctrl, 0xf, 0xf, false);\
    bool _gt = (_nh > (hi)) || (_nh == (hi) && _nl > (lo));                   \
    hi = _gt ? _nh : (hi);                                                    \
    lo = _gt ? _nl : (lo);                                                    \
  }

// 16-lane reductions (only lane 15 mod 16 result is consumed)
#define DPP_RED16(v, OP)                                                      \
  {                                                                           \
    int _i;                                                                   \
    _i = __builtin_amdgcn_update_dpp(__float_as_int(v), __float_as_int(v), 0x111, 0xf, 0xf, false); \
    v = OP(v, __int_as_float(_i));                                            \
    _i = __builtin_amdgcn_update_dpp(__float_as_int(v), __float_as_int(v), 0x112, 0xf, 0xf, false); \
    v = OP(v, __int_as_float(_i));                                            \
    _i = __builtin_amdgcn_update_dpp(__float_as_int(v), __float_as_int(v), 0x114, 0xf, 0xf, false); \
    v = OP(v, __int_as_float(_i));                                            \
    _i = __builtin_amdgcn_update_dpp(__float_as_int(v), __float_as_int(v), 0x118, 0xf, 0xf, false); \
    v = OP(v, __int_as_float(_i));                                            \
  }

__device__ __forceinline__ float fadd_op(float a, float b) { return a + b; }

__global__ __launch_bounds__(512) void fps_pgemm_query_kernel(
    const float* __restrict__ xyz, float* __restrict__ out_newxyz,
    float* __restrict__ ws_newxyz, const float* __restrict__ points,
    const float* __restrict__ W0, const float* __restrict__ b0g,
    unsigned short* __restrict__ P1, unsigned short* __restrict__ y0g,
    float* __restrict__ partials, int* __restrict__ prog,
    int* __restrict__ pdone) {
  __shared__ __align__(16) char smem[82048];  // >80KiB -> 1 block/CU
  const int t = threadIdx.x;

  if (blockIdx.x < 8) {
    // ---------------- FPS (R15 chain) + chunked publication ----------
    float4* sXYZ4 = (float4*)smem;                                 // 65536 B
    volatile unsigned long long* vRed =
        (volatile unsigned long long*)(smem + 65536);              // 128 B
    int* sWidx = (int*)(smem + 65664);                             // 4096 B
    const int b = blockIdx.x;
    const int wave = t >> 6;
    const int lane = t & 63;
    const float* xb = xyz + (size_t)b * 3 * NPTS;

    for (int i = t; i < NPTS; i += 512) {
      sXYZ4[i] = make_float4(xb[i], xb[NPTS + i], xb[2 * NPTS + i], 0.f);
    }
    if (t == 0) sWidx[0] = 0;
    if (t < 16) vRed[t] = 0xFFFFFFFFFFFFFFFFull;  // tag field = invalid

    float px[8], py[8], pz[8], dist[8];
    {
      float4 a0 = ((const float4*)xb)[2 * t];
      float4 a1 = ((const float4*)xb)[2 * t + 1];
      float4 b0v = ((const float4*)(xb + NPTS))[2 * t];
      float4 b1v = ((const float4*)(xb + NPTS))[2 * t + 1];
      float4 c0 = ((const float4*)(xb + 2 * NPTS))[2 * t];
      float4 c1 = ((const float4*)(xb + 2 * NPTS))[2 * t + 1];
      px[0] = a0.x; px[1] = a0.y; px[2] = a0.z; px[3] = a0.w;
      px[4] = a1.x; px[5] = a1.y; px[6] = a1.z; px[7] = a1.w;
      py[0] = b0v.x; py[1] = b0v.y; py[2] = b0v.z; py[3] = b0v.w;
      py[4] = b1v.x; py[5] = b1v.y; py[6] = b1v.z; py[7] = b1v.w;
      pz[0] = c0.x; pz[1] = c0.y; pz[2] = c0.z; pz[3] = c0.w;
      pz[4] = c1.x; pz[5] = c1.y; pz[6] = c1.z; pz[7] = c1.w;
    }
#pragma unroll
    for (int j = 0; j < 8; ++j) dist[j] = 1e10f;

    float cx = xb[0], cy = xb[NPTS], cz = xb[2 * NPTS];  // centroid 0

    __syncthreads();  // sXYZ4 + vRed init visible to all waves

    for (int s = 0; s < NS - 1; ++s) {
#pragma unroll
      for (int j = 0; j < 8; ++j) {
        float dx = __fadd_rn(px[j], -cx);
        float dy = __fadd_rn(py[j], -cy);
        float dz = __fadd_rn(pz[j], -cz);
        float d = __fadd_rn(__fadd_rn(__fmul_rn(dx, dx), __fmul_rn(dy, dy)),
                            __fmul_rn(dz, dz));
        dist[j] = fminf(dist[j], d);
      }
      float m = fmaxf(fmaxf(fmaxf(dist[0], dist[1]), fmaxf(dist[2], dist[3])),
                      fmaxf(fmaxf(dist[4], dist[5]), fmaxf(dist[6], dist[7])));
      int v = __float_as_int(m);
      DPP_IMAX(v, 0x111)
      DPP_IMAX(v, 0x112)
      DPP_IMAX(v, 0x114)
      DPP_IMAX(v, 0x118)
      DPP_IMAX(v, 0x142)
      DPP_IMAX(v, 0x143)
      const int wm_i = __builtin_amdgcn_readlane(v, 63);
      const float wm = __int_as_float(wm_i);
      unsigned long long claim = __ballot(m == wm);
      int firstlane = __ffsll(claim) - 1;
      const int par = s & 1;
      if (lane == firstlane) {
        int j = 7;
#pragma unroll
        for (int jj = 6; jj >= 0; --jj)
          if (dist[jj] == wm) j = jj;
        unsigned widx = (unsigned)(t * 8 + j);
        unsigned lo = ((unsigned)s << 12) | (4095u - widx);
        vRed[par * 8 + wave] =
            ((unsigned long long)(unsigned)wm_i << 32) | (unsigned long long)lo;
      }
      // data-flow sync: poll the 8 slots until all carry tag s
      unsigned long long k;
      for (;;) {
        k = vRed[par * 8 + (lane & 7)];
        bool ok = (((unsigned)k) >> 12) == (unsigned)s;
        if (__ballot(ok) == ~0ull) break;
      }
      unsigned h2 = (unsigned)(k >> 32), l2 = (unsigned)k;
      // lanes 0-7 prefetch their slot's coords; overlaps the DPP reduce.
      float4 scoord;
      if (lane < 8) scoord = sXYZ4[4095 - (int)(l2 & 0xFFFu)];
      DPP_U64MAX(h2, l2, 0x111)
      DPP_U64MAX(h2, l2, 0x112)
      DPP_U64MAX(h2, l2, 0x114)
      const unsigned gl = (unsigned)__builtin_amdgcn_readlane((int)l2, 7);
      const int widx = 4095 - (int)(gl & 0xFFFu);
      const int wslot = widx >> 9;  // winning wave = widx/512
      cx = __int_as_float(__builtin_amdgcn_readlane(__float_as_int(scoord.x), wslot));
      cy = __int_as_float(__builtin_amdgcn_readlane(__float_as_int(scoord.y), wslot));
      cz = __int_as_float(__builtin_amdgcn_readlane(__float_as_int(scoord.z), wslot));
      if (t == 0) sWidx[s + 1] = widx;
      // publish centroids [s-63 .. s] every 64 steps (wave 0 only; the
      // release store's vmcnt drain covers wave 0's lane stores).
      if ((s & 63) == 63) {
        if (t < 64) {
          int w = sWidx[(s - 63) + t];
          float4 c = sXYZ4[w];
          float* dst = ws_newxyz + ((size_t)((b << 10) + (s - 63) + t)) * 3;
          dst[0] = c.x; dst[1] = c.y; dst[2] = c.z;
        }
        if (t == 0)
          __hip_atomic_store(&prog[b], s + 1, __ATOMIC_RELEASE,
                             __HIP_MEMORY_SCOPE_AGENT);
      }
    }
    __syncthreads();
    // publish the last chunk [960..1023]
    if (t < 64) {
      int w = sWidx[960 + t];
      float4 c = sXYZ4[w];
      float* dst = ws_newxyz + ((size_t)((b << 10) + 960 + t)) * 3;
      dst[0] = c.x; dst[1] = c.y; dst[2] = c.z;
    }
    if (t == 0)
      __hip_atomic_store(&prog[b], 1024, __ATOMIC_RELEASE,
                         __HIP_MEMORY_SCOPE_AGENT);
    for (int s2 = t; s2 < NS; s2 += 512) {
      int w = sWidx[s2];
      float4 c = sXYZ4[w];
      out_newxyz[b * 3 * NS + s2] = c.x;
      out_newxyz[b * 3 * NS + NS + s2] = c.y;
      out_newxyz[b * 3 * NS + 2 * NS + s2] = c.z;
    }
  } else {
    // ---------------- worker: pgemm tiles, then query pairs ----------
    const int i = blockIdx.x - 8;  // 0..247
    float* sP = (float*)smem;            // 16384 B  [c][n]
    float* sW = (float*)(smem + 16384);  // 17408 B  [c][o] pitch 68
    float* sB = (float*)(smem + 33792);  // 256 B
    if (t < 64) sB[t] = b0g[t];
    int ntiles = 0;
    for (int tile = i; tile < 512; tile += 248) {
      ++ntiles;
      const int bb = tile >> 6;
      const int n0 = (tile & 63) * 64;
      const float* pb = points + (size_t)bb * ND * NPTS;
      __syncthreads();  // protect sP/sW from previous tile's readers
      for (int f = t; f < 4096; f += 512) {
        int c = f >> 6, n = f & 63;
        sP[f] = pb[c * NPTS + n0 + n];
      }
      for (int f = t; f < 4096; f += 512) {
        int c = f >> 6, o = f & 63;
        sW[c * 68 + o] = W0[o * 67 + 3 + c];
      }
      __syncthreads();
      if (t < 256) {
        const int nl = (t & 15) * 4;
        const int ol = (t >> 4) * 4;
        float acc[4][4];
#pragma unroll
        for (int a = 0; a < 4; ++a)
#pragma unroll
          for (int j = 0; j < 4; ++j) acc[a][j] = 0.f;
#pragma unroll 4
        for (int c = 0; c < 64; ++c) {
          float4 xv = *(const float4*)(sP + c * 64 + nl);
          float4 wv = *(const float4*)(sW + c * 68 + ol);
          float xa[4] = {xv.x, xv.y, xv.z, xv.w};
          float wa[4] = {wv.x, wv.y, wv.z, wv.w};
#pragma unroll
          for (int a = 0; a < 4; ++a)
#pragma unroll
            for (int j = 0; j < 4; ++j) acc[a][j] += xa[a] * wa[j];
        }
#pragma unroll
        for (int a = 0; a < 4; ++a) {
          ushort4 v;
          v.x = (unsigned short)f2bf(acc[a][0] + sB[ol + 0]);
          v.y = (unsigned short)f2bf(acc[a][1] + sB[ol + 1]);
          v.z = (unsigned short)f2bf(acc[a][2] + sB[ol + 2]);
          v.w = (unsigned short)f2bf(acc[a][3] + sB[ol + 3]);
          *(ushort4*)(P1 + ((size_t)(bb << 12) + n0 + nl + a) * 64 + ol) = v;
        }
      }
    }
    __syncthreads();  // all P1 stores of this block complete (pre-barrier drain)
    if (t == 0)
      __hip_atomic_fetch_add(pdone, ntiles, __ATOMIC_RELEASE,
                             __HIP_MEMORY_SCOPE_AGENT);
    // wait for ALL 512 pgemm tiles (P1 fully written)
    while (__hip_atomic_load(pdone, __ATOMIC_ACQUIRE,
                             __HIP_MEMORY_SCOPE_AGENT) < 512) {
      __builtin_amdgcn_s_sleep(2);
    }
    __syncthreads();

    // ---------------- query phase: per-wave pairs --------------------
    const int wavei = t >> 6;
    const int lane = t & 63;
    int* sIdxW = (int*)smem + wavei * 32;  // wave-private 128 B
    const float wx = W0[lane * 67 + 0];
    const float wy = W0[lane * 67 + 1];
    const float wz = W0[lane * 67 + 2];
    const float r2 = (float)(0.4 * 0.4);
    for (int p = i * 8 + wavei; p < 8192; p += 1984) {
      const int b = p >> 10;
      const int s = p & 1023;
      while (__hip_atomic_load(&prog[b], __ATOMIC_ACQUIRE,
                               __HIP_MEMORY_SCOPE_AGENT) <= s) {
        __builtin_amdgcn_s_sleep(32);
      }
      const float* xb = xyz + (size_t)b * 3 * NPTS;
      const float cx = ws_newxyz[p * 3 + 0];
      const float cy = ws_newxyz[p * 3 + 1];
      const float cz = ws_newxyz[p * 3 + 2];
      const float ss = __fadd_rn(
          __fadd_rn(__fmul_rn(cx, cx), __fmul_rn(cy, cy)), __fmul_rn(cz, cz));
      int cnt = 0;
      for (int ci = 0; ci < 64 && cnt < 32; ++ci) {
        int n = ci * 64 + lane;
        float x = xb[n], y = xb[NPTS + n], z = xb[2 * NPTS + n];
        float dot = __fadd_rn(__fadd_rn(__fmul_rn(cx, x), __fmul_rn(cy, y)),
                              __fmul_rn(cz, z));
        float dd = __fadd_rn(__fadd_rn(__fmul_rn(x, x), __fmul_rn(y, y)),
                             __fmul_rn(z, z));
        float d = __fmul_rn(-2.0f, dot);
        d = __fadd_rn(d, ss);
        d = __fadd_rn(d, dd);
        d = fmaxf(d, 1e-12f);  // clip
        bool inc = (d <= r2);
        unsigned long long m = __ballot(inc);
        int slot = cnt + (int)__popcll(m & ((1ull << lane) - 1ull));
        if (inc && slot < 32) sIdxW[slot] = n;
        cnt += (int)__popcll(m);
      }
      if (lane < 32) {
        int v;
        if (lane < cnt) v = sIdxW[lane];
        else v = (cnt > 0) ? sIdxW[0] : 0;
        sIdxW[lane] = v;
      }
      float ssum = 0.f, ssq = 0.f;
      unsigned short* y0p = y0g + (size_t)p * 2048;
      for (int r = 0; r < 32; ++r) {
        const int n = sIdxW[r];
        float P1v = bf2f(P1[((size_t)(b << 12) + n) * 64 + lane]);
        float dx = __fadd_rn(xb[n], -cx);
        float dy = __fadd_rn(xb[NPTS + n], -cy);
        float dz = __fadd_rn(xb[2 * NPTS + n], -cz);
        float y = P1v + (dx * wx + dy * wy + dz * wz);
        y0p[r * 64 + lane] = (unsigned short)f2bf(y);
        ssum += y;
        ssq += y * y;
      }
      partials[(size_t)p * 128 + lane] = ssum;
      partials[(size_t)p * 128 + 64 + lane] = ssq;
    }
  }
}

// ------------------------------------------------------------------
// conv1 via MFMA bf16 — stages y0 flat, BN0+ReLU from LDS scale/shift
// ------------------------------------------------------------------
__global__ __launch_bounds__(256) void conv1_mfma_kernel(
    const unsigned short* __restrict__ y0, const float* __restrict__ W1,
    const float* __restrict__ b1, const float* __restrict__ scaleA,
    const float* __restrict__ shiftA, unsigned short* __restrict__ y1,
    float* __restrict__ partials) {
  __shared__ __align__(16) short sW1b[64 * 72];   // 9216 B
  __shared__ __align__(16) short sXb[128 * 72];   // 18432 B
  __shared__ float sScale[64], sShift[64], sBias[64];

  const int t = threadIdx.x;
  const int wv = t >> 6, lane = t & 63;
  const int quad = lane >> 4, l15 = lane & 15;
  const int pair0 = blockIdx.x * 4;

  if (t < 64) { sScale[t] = scaleA[t]; sShift[t] = shiftA[t]; sBias[t] = b1[t]; }
  for (int f = t; f < 4096; f += 256) sW1b[(f >> 6) * 72 + (f & 63)] = f2bf(W1[f]);
  __syncthreads();  // sScale/sShift visible before staging reads them

  const unsigned short* y0b = y0 + (size_t)pair0 * 2048;
  for (int f = t; f < 2048; f += 256) {
    ushort4 v4 = ((const ushort4*)y0b)[f];
    const int row = f >> 4, c4 = (f & 15) * 4;
    short4 o4;
    o4.x = f2bf(fmaxf(bf2f(v4.x) * sScale[c4 + 0] + sShift[c4 + 0], 0.f));
    o4.y = f2bf(fmaxf(bf2f(v4.y) * sScale[c4 + 1] + sShift[c4 + 1], 0.f));
    o4.z = f2bf(fmaxf(bf2f(v4.z) * sScale[c4 + 2] + sShift[c4 + 2], 0.f));
    o4.w = f2bf(fmaxf(bf2f(v4.w) * sScale[c4 + 3] + sShift[c4 + 3], 0.f));
    *(short4*)(sXb + row * 72 + c4) = o4;
  }
  __syncthreads();

  f32x4 acc[8];
#pragma unroll
  for (int i = 0; i < 8; ++i) acc[i] = (f32x4){0.f, 0.f, 0.f, 0.f};
#pragma unroll
  for (int kh = 0; kh < 2; ++kh) {
    const int kc = kh * 32 + quad * 8;
    bf16x8 A = *(const bf16x8*)(sW1b + (wv * 16 + l15) * 72 + kc);
#pragma unroll
    for (int ti = 0; ti < 8; ++ti) {
      bf16x8 B = *(const bf16x8*)(sXb + (ti * 16 + l15) * 72 + kc);
      acc[ti] = __builtin_amdgcn_mfma_f32_16x16x32_bf16(A, B, acc[ti], 0, 0, 0);
    }
  }

#pragma unroll
  for (int reg = 0; reg < 4; ++reg) {
    const int m = wv * 16 + quad * 4 + reg;
    const float bb = sBias[m];
    float v[8];
#pragma unroll
    for (int ti = 0; ti < 8; ++ti) {
      v[ti] = acc[ti][reg] + bb;
      y1[(size_t)(pair0 + (ti >> 1)) * 2048 + m * 32 + (ti & 1) * 16 + l15] =
          (unsigned short)f2bf(v[ti]);
    }
    float s1 = ((v[0] + v[1]) + (v[2] + v[3])) + ((v[4] + v[5]) + (v[6] + v[7]));
    float s2 = ((v[0] * v[0] + v[1] * v[1]) + (v[2] * v[2] + v[3] * v[3])) +
               ((v[4] * v[4] + v[5] * v[5]) + (v[6] * v[6] + v[7] * v[7]));
    DPP_RED16(s1, fadd_op)
    DPP_RED16(s2, fadd_op)
    if (l15 == 15) {
      partials[(size_t)blockIdx.x * 128 + m] = s1;
      partials[(size_t)blockIdx.x * 128 + 64 + m] = s2;
    }
  }
}

// ------------------------------------------------------------------
// conv2 via MFMA bf16 (unchanged from R21)
// ------------------------------------------------------------------
__global__ __launch_bounds__(256) void conv2_mfma_kernel(
    const unsigned short* __restrict__ y1, const float* __restrict__ W2,
    const float* __restrict__ b2, const float* __restrict__ scaleA,
    const float* __restrict__ shiftA, float* __restrict__ pmaxT,
    float* __restrict__ pminT, float* __restrict__ partials) {
  __shared__ __align__(16) short sW2[128 * 72];  // 18432 B, [o][c] pitch 72
  __shared__ __align__(16) short sXb[128 * 72];  // 18432 B, 4 s x [n][c]
  __shared__ float sScale[64], sShift[64], sBias[128];

  const int t = threadIdx.x;
  const int pair0 = blockIdx.x * 4;
  const int lane = t & 63;
  const int wv = t >> 6;
  const int quad = lane >> 4;
  const int l15 = lane & 15;

  if (t < 64) { sScale[t] = scaleA[t]; sShift[t] = shiftA[t]; }
  if (t < 128) sBias[t] = b2[t];
  __syncthreads();  // sScale/sShift visible before staging reads them
  for (int f = t; f < 8192; f += 256) {
    int o = f >> 6, c = f & 63;
    sW2[o * 72 + c] = f2bf(W2[f]);
  }
  for (int f = t; f < 8192; f += 256) {
    int si = f >> 11;
    int rmd = f & 2047;
    int o = rmd >> 5, k = rmd & 31;
    float v = bf2f(y1[(size_t)(pair0 + si) * 2048 + rmd]);
    v = v * sScale[o] + sShift[o];
    v = fmaxf(v, 0.f);
    sXb[(si * 32 + k) * 72 + o] = f2bf(v);
  }
  __syncthreads();

  f32x4 acc[2][8];
#pragma unroll
  for (int i = 0; i < 2; ++i)
#pragma unroll
    for (int ti = 0; ti < 8; ++ti) acc[i][ti] = (f32x4){0.f, 0.f, 0.f, 0.f};
#pragma unroll
  for (int kh = 0; kh < 2; ++kh) {
    const int kc = kh * 32 + quad * 8;
    bf16x8 A0 = *(const bf16x8*)(sW2 + (wv * 32 + l15) * 72 + kc);
    bf16x8 A1 = *(const bf16x8*)(sW2 + (wv * 32 + 16 + l15) * 72 + kc);
#pragma unroll
    for (int ti = 0; ti < 8; ++ti) {
      bf16x8 B = *(const bf16x8*)(sXb + (ti * 16 + l15) * 72 + kc);
      acc[0][ti] = __builtin_amdgcn_mfma_f32_16x16x32_bf16(A0, B, acc[0][ti], 0, 0, 0);
      acc[1][ti] = __builtin_amdgcn_mfma_f32_16x16x32_bf16(A1, B, acc[1][ti], 0, 0, 0);
    }
  }

#pragma unroll
  for (int i = 0; i < 2; ++i) {
#pragma unroll
    for (int reg = 0; reg < 4; ++reg) {
      const int m = wv * 32 + i * 16 + quad * 4 + reg;
      const float bb = sBias[m];
      float v[8];
#pragma unroll
      for (int ti = 0; ti < 8; ++ti) v[ti] = acc[i][ti][reg] + bb;
      float s1 = ((v[0] + v[1]) + (v[2] + v[3])) + ((v[4] + v[5]) + (v[6] + v[7]));
      float s2 = ((v[0] * v[0] + v[1] * v[1]) + (v[2] * v[2] + v[3] * v[3])) +
                 ((v[4] * v[4] + v[5] * v[5]) + (v[6] * v[6] + v[7] * v[7]));
      DPP_RED16(s1, fadd_op)
      DPP_RED16(s2, fadd_op)
      if (l15 == 15) {
        partials[(size_t)blockIdx.x * 256 + m] = s1;
        partials[(size_t)blockIdx.x * 256 + 128 + m] = s2;
      }
#pragma unroll
      for (int si = 0; si < 4; ++si) {
        float mx = fmaxf(v[2 * si], v[2 * si + 1]);
        float mn = fminf(v[2 * si], v[2 * si + 1]);
        DPP_RED16(mx, fmaxf)
        DPP_RED16(mn, fminf)
        if (l15 == 15) {
          pmaxT[(size_t)m * 8192 + pair0 + si] = mx;
          pminT[(size_t)m * 8192 + pair0 + si] = mn;
        }
      }
    }
  }
}

// one block per channel: f64 reduce -> fused scale/shift for next layer
template <int COUT>
__global__ __launch_bounds__(256) void stats_kernel(const float* __restrict__ partials,
                                                    int nblocks,
                                                    const float* __restrict__ gA,
                                                    const float* __restrict__ btA,
                                                    float* __restrict__ scaleA,
                                                    float* __restrict__ shiftA) {
  const int o = blockIdx.x;
  const int t = threadIdx.x;
  double s1 = 0.0, s2 = 0.0;
  for (int blk = t; blk < nblocks; blk += 256) {
    s1 += (double)partials[(size_t)blk * (COUT * 2) + o];
    s2 += (double)partials[(size_t)blk * (COUT * 2) + COUT + o];
  }
  __shared__ double r1[256], r2[256];
  r1[t] = s1; r2[t] = s2;
  __syncthreads();
  for (int st = 128; st > 0; st >>= 1) {
    if (t < st) { r1[t] += r1[t + st]; r2[t] += r2[t + st]; }
    __syncthreads();
  }
  if (t == 0) {
    const double Nr = 262144.0;  // B*K*S
    double mean = r1[0] / Nr;
    double var = r2[0] / Nr - mean * mean;
    double rstd = 1.0 / sqrt(var + 1e-5);
    double sc = rstd * (double)gA[o];
    scaleA[o] = (float)sc;
    shiftA[o] = (float)((double)btA[o] - mean * sc);
  }
}

// layer-2 stats + final normalize fused: one block per channel (128).
__global__ __launch_bounds__(256) void stats_final_kernel(
    const float* __restrict__ partials, int nblocks,
    const float* __restrict__ pmaxT, const float* __restrict__ pminT,
    const float* __restrict__ gA, const float* __restrict__ btA,
    float* __restrict__ out) {
  const int o = blockIdx.x;
  const int t = threadIdx.x;
  double s1 = 0.0, s2 = 0.0;
  for (int blk = t; blk < nblocks; blk += 256) {
    s1 += (double)partials[(size_t)blk * 256 + o];
    s2 += (double)partials[(size_t)blk * 256 + 128 + o];
  }
  __shared__ double r1[256], r2[256];
  __shared__ float sMean, sRstd;
  r1[t] = s1; r2[t] = s2;
  __syncthreads();
  for (int st = 128; st > 0; st >>= 1) {
    if (t < st) { r1[t] += r1[t + st]; r2[t] += r2[t + st]; }
    __syncthreads();
  }
  if (t == 0) {
    const double Nr = 262144.0;
    double mean = r1[0] / Nr;
    double var = r2[0] / Nr - mean * mean;
    sMean = (float)mean;
    sRstd = (float)(1.0 / sqrt(var + 1e-5));
  }
  __syncthreads();
  const float mn = sMean, rs = sRstd, gg = gA[o], bb = btA[o];
  const float slope = rs * gg;
  const float* src = (slope >= 0.f) ? pmaxT : pminT;
  for (int i = t; i < NB * NS; i += 256) {
    int b = i >> 10;
    int s = i & 1023;
    float v = src[(size_t)o * 8192 + i];
    float t1 = (v - mn) * rs;
    float t2 = t1 * gg + bb;
    out[(size_t)b * (128 * NS) + o * NS + s] = fmaxf(t2, 0.f);
  }
}

extern "C" void kernel_launch(void* const* d_in, const int* in_sizes, int n_in,
                              void* d_out, int out_size, void* d_ws, size_t ws_size,
                              hipStream_t stream) {
  (void)in_sizes; (void)n_in; (void)out_size; (void)ws_size;
  const float* xyz = (const float*)d_in[0];
  const float* points = (const float*)d_in[1];
  const float* W0 = (const float*)d_in[2];
  const float* b0 = (const float*)d_in[3];
  const float* g0 = (const float*)d_in[4];
  const float* bt0 = (const float*)d_in[5];
  const float* W1 = (const float*)d_in[6];
  const float* b1 = (const float*)d_in[7];
  const float* g1 = (const float*)d_in[8];
  const float* bt1 = (const float*)d_in[9];
  const float* W2 = (const float*)d_in[10];
  const float* b2 = (const float*)d_in[11];
  const float* g2 = (const float*)d_in[12];
  const float* bt2 = (const float*)d_in[13];
  float* out = (float*)d_out;

  float* ws = (float*)d_ws;
  size_t off = 0;
  float* newxyz = ws + off;  off += (size_t)NB * NS * 3;
  unsigned short* P1 = (unsigned short*)(ws + off);
  off += (size_t)NB * NPTS * 64;  // alloc as before; bf16 uses half
  unsigned short* y0 = (unsigned short*)(ws + off);
  off += (size_t)8192 * 1024;  // 8192 pairs x 2048 bf16 = 32MB
  unsigned short* y1 = (unsigned short*)(ws + off);
  off += (size_t)NB * NS * 1024;  // 8192 x 2048 bf16 = 32MB
  float* partials = ws + off; off += (size_t)8192 * 256;
  float* scaleA = ws + off;  off += 128;
  float* shiftA = ws + off;  off += 128;
  float* pmaxT = ws + off;   off += (size_t)128 * NB * NS;
  float* pminT = ws + off;   off += (size_t)128 * NB * NS;
  int* prog = (int*)(ws + off); off += 16;  // 8 prog + 1 pdone (+pad)
  int* pdone = prog + 8;

  // reset pipeline counters (stream-ordered, graph-capturable)
  hipMemsetAsync(prog, 0, 64, stream);

  {
    void* kargs[] = {(void*)&xyz,  (void*)&out,      (void*)&newxyz,
                     (void*)&points, (void*)&W0,     (void*)&b0,
                     (void*)&P1,   (void*)&y0,       (void*)&partials,
                     (void*)&prog, (void*)&pdone};
    hipLaunchCooperativeKernel(fps_pgemm_query_kernel, dim3(256), dim3(512),
                               kargs, 0, stream);
  }
  stats_kernel<64><<<64, 256, 0, stream>>>(partials, 8192, g0, bt0, scaleA, shiftA);
  conv1_mfma_kernel<<<2048, 256, 0, stream>>>(y0, W1, b1, scaleA, shiftA, y1,
                                              partials);
  stats_kernel<64><<<64, 256, 0, stream>>>(partials, 2048, g1, bt1, scaleA, shiftA);
  conv2_mfma_kernel<<<2048, 256, 0, stream>>>(y1, W2, b2, scaleA, shiftA,
                                              pmaxT, pminT, partials);
  stats_final_kernel<<<128, 256, 0, stream>>>(partials, 2048, pmaxT, pminT,
                                              g2, bt2, out + NB * NS * 3);
}

// Round 11
// 883.116 us; speedup vs baseline: 1.2031x; 1.2031x over previous
//
#include <hip/hip_runtime.h>
#include <cstddef>
#include <cstdint>

#define NB 8
#define NPTS 4096
#define NS 1024
#define NK 32
#define ND 64

typedef __attribute__((ext_vector_type(8))) short bf16x8;  // 8 bf16 (4 VGPRs)
typedef __attribute__((ext_vector_type(4))) float f32x4;

__device__ __forceinline__ short f2bf(float f) {  // RNE f32->bf16
  unsigned u = __float_as_uint(f);
  u += 0x7FFF + ((u >> 16) & 1);
  return (short)(u >> 16);
}

__device__ __forceinline__ float bf2f(unsigned short u) {
  return __uint_as_float((unsigned)u << 16);
}

// ------------------------------------------------------------------
// R23 = R21 verbatim (session best, 885us verified). R22's pipeline
// overlap is abandoned with mechanism: the fps serial chain slowed
// 677->~830us when 248 worker CUs stayed active (clock boost loss ~20%
// on a latency-bound chain) -- 8x larger than the hidden query work.
// Structural floor: fps 677us (1023-step sequential argmax) + ~208us
// launch-structured tail.
// ------------------------------------------------------------------
#define DPP_IMAX(v, ctrl)                                                     \
  {                                                                           \
    int _o = __builtin_amdgcn_update_dpp(v, v, ctrl, 0xf, 0xf, false);        \
    v = (_o > v) ? _o : v;                                                    \
  }

#define DPP_U64MAX(hi, lo, ctrl)                                              \
  {                                                                           \
    unsigned _nh = (unsigned)__builtin_amdgcn_update_dpp((int)(hi), (int)(hi),\
                                                         ctrl, 0xf, 0xf, false);\
    unsigned _nl = (unsigned)__builtin_amdgcn_update_dpp((int)(lo), (int)(lo),\
                                                         ctrl, 0xf, 0xf, false);\
    bool _gt = (_nh > (hi)) || (_nh == (hi) && _nl > (lo));                   \
    hi = _gt ? _nh : (hi);                                                    \
    lo = _gt ? _nl : (lo);                                                    \
  }

// 16-lane reductions (only lane 15 mod 16 result is consumed)
#define DPP_RED16(v, OP)                                                      \
  {                                                                           \
    int _i;                                                                   \
    _i = __builtin_amdgcn_update_dpp(__float_as_int(v), __float_as_int(v), 0x111, 0xf, 0xf, false); \
    v = OP(v, __int_as_float(_i));                                            \
    _i = __builtin_amdgcn_update_dpp(__float_as_int(v), __float_as_int(v), 0x112, 0xf, 0xf, false); \
    v = OP(v, __int_as_float(_i));                                            \
    _i = __builtin_amdgcn_update_dpp(__float_as_int(v), __float_as_int(v), 0x114, 0xf, 0xf, false); \
    v = OP(v, __int_as_float(_i));                                            \
    _i = __builtin_amdgcn_update_dpp(__float_as_int(v), __float_as_int(v), 0x118, 0xf, 0xf, false); \
    v = OP(v, __int_as_float(_i));                                            \
  }

__device__ __forceinline__ float fadd_op(float a, float b) { return a + b; }

__global__ __launch_bounds__(512) void fps_pgemm_kernel(
    const float* __restrict__ xyz, float* __restrict__ out_newxyz,
    float* __restrict__ ws_newxyz, const float* __restrict__ points,
    const float* __restrict__ W0, const float* __restrict__ b0g,
    unsigned short* __restrict__ P1) {
  __shared__ __align__(16) char smem[69760];
  const int t = threadIdx.x;

  if (blockIdx.x < 8) {
    // ---------------- FPS ----------------
    float4* sXYZ4 = (float4*)smem;                                 // 65536 B
    volatile unsigned long long* vRed =
        (volatile unsigned long long*)(smem + 65536);              // 128 B [par][wave]
    int* sWidx = (int*)(smem + 65664);                             // 4096 B
    const int b = blockIdx.x;
    const int wave = t >> 6;
    const int lane = t & 63;
    const float* xb = xyz + (size_t)b * 3 * NPTS;

    for (int i = t; i < NPTS; i += 512) {
      sXYZ4[i] = make_float4(xb[i], xb[NPTS + i], xb[2 * NPTS + i], 0.f);
    }
    if (t == 0) sWidx[0] = 0;
    if (t < 16) vRed[t] = 0xFFFFFFFFFFFFFFFFull;  // tag field = invalid

    float px[8], py[8], pz[8], dist[8];
    {
      float4 a0 = ((const float4*)xb)[2 * t];
      float4 a1 = ((const float4*)xb)[2 * t + 1];
      float4 b0v = ((const float4*)(xb + NPTS))[2 * t];
      float4 b1v = ((const float4*)(xb + NPTS))[2 * t + 1];
      float4 c0 = ((const float4*)(xb + 2 * NPTS))[2 * t];
      float4 c1 = ((const float4*)(xb + 2 * NPTS))[2 * t + 1];
      px[0] = a0.x; px[1] = a0.y; px[2] = a0.z; px[3] = a0.w;
      px[4] = a1.x; px[5] = a1.y; px[6] = a1.z; px[7] = a1.w;
      py[0] = b0v.x; py[1] = b0v.y; py[2] = b0v.z; py[3] = b0v.w;
      py[4] = b1v.x; py[5] = b1v.y; py[6] = b1v.z; py[7] = b1v.w;
      pz[0] = c0.x; pz[1] = c0.y; pz[2] = c0.z; pz[3] = c0.w;
      pz[4] = c1.x; pz[5] = c1.y; pz[6] = c1.z; pz[7] = c1.w;
    }
#pragma unroll
    for (int j = 0; j < 8; ++j) dist[j] = 1e10f;

    float cx = xb[0], cy = xb[NPTS], cz = xb[2 * NPTS];  // centroid 0

    __syncthreads();  // sXYZ4 + vRed init visible to all waves

    for (int s = 0; s < NS - 1; ++s) {
#pragma unroll
      for (int j = 0; j < 8; ++j) {
        float dx = __fadd_rn(px[j], -cx);
        float dy = __fadd_rn(py[j], -cy);
        float dz = __fadd_rn(pz[j], -cz);
        float d = __fadd_rn(__fadd_rn(__fmul_rn(dx, dx), __fmul_rn(dy, dy)),
                            __fmul_rn(dz, dz));
        dist[j] = fminf(dist[j], d);
      }
      float m = fmaxf(fmaxf(fmaxf(dist[0], dist[1]), fmaxf(dist[2], dist[3])),
                      fmaxf(fmaxf(dist[4], dist[5]), fmaxf(dist[6], dist[7])));
      int v = __float_as_int(m);
      DPP_IMAX(v, 0x111)
      DPP_IMAX(v, 0x112)
      DPP_IMAX(v, 0x114)
      DPP_IMAX(v, 0x118)
      DPP_IMAX(v, 0x142)
      DPP_IMAX(v, 0x143)
      const int wm_i = __builtin_amdgcn_readlane(v, 63);
      const float wm = __int_as_float(wm_i);
      unsigned long long claim = __ballot(m == wm);
      int firstlane = __ffsll(claim) - 1;
      const int par = s & 1;
      if (lane == firstlane) {
        int j = 7;
#pragma unroll
        for (int jj = 6; jj >= 0; --jj)
          if (dist[jj] == wm) j = jj;
        unsigned widx = (unsigned)(t * 8 + j);
        unsigned lo = ((unsigned)s << 12) | (4095u - widx);
        vRed[par * 8 + wave] =
            ((unsigned long long)(unsigned)wm_i << 32) | (unsigned long long)lo;
      }
      // data-flow sync: poll the 8 slots until all carry tag s
      unsigned long long k;
      for (;;) {
        k = vRed[par * 8 + (lane & 7)];
        bool ok = (((unsigned)k) >> 12) == (unsigned)s;
        if (__ballot(ok) == ~0ull) break;
      }
      unsigned h2 = (unsigned)(k >> 32), l2 = (unsigned)k;
      // lanes 0-7 prefetch their slot's coords; overlaps the DPP reduce.
      float4 scoord;
      if (lane < 8) scoord = sXYZ4[4095 - (int)(l2 & 0xFFFu)];
      DPP_U64MAX(h2, l2, 0x111)
      DPP_U64MAX(h2, l2, 0x112)
      DPP_U64MAX(h2, l2, 0x114)
      const unsigned gl = (unsigned)__builtin_amdgcn_readlane((int)l2, 7);
      const int widx = 4095 - (int)(gl & 0xFFFu);
      const int wslot = widx >> 9;  // winning wave = widx/512
      cx = __int_as_float(__builtin_amdgcn_readlane(__float_as_int(scoord.x), wslot));
      cy = __int_as_float(__builtin_amdgcn_readlane(__float_as_int(scoord.y), wslot));
      cz = __int_as_float(__builtin_amdgcn_readlane(__float_as_int(scoord.z), wslot));
      if (t == 0) sWidx[s + 1] = widx;
    }
    __syncthreads();
    for (int s2 = t; s2 < NS; s2 += 512) {
      int w = sWidx[s2];
      float4 c = sXYZ4[w];
      out_newxyz[b * 3 * NS + s2] = c.x;
      out_newxyz[b * 3 * NS + NS + s2] = c.y;
      out_newxyz[b * 3 * NS + 2 * NS + s2] = c.z;
      ws_newxyz[((b << 10) + s2) * 3 + 0] = c.x;
      ws_newxyz[((b << 10) + s2) * 3 + 1] = c.y;
      ws_newxyz[((b << 10) + s2) * 3 + 2] = c.z;
    }
  } else {
    // ---------------- pgemm: P1[b][n][o] = points·W0[:,3:] + b0 (bf16) ----
    float* sP = (float*)smem;            // 16384 B  [c][n]
    float* sW = (float*)(smem + 16384);  // 17408 B  [c][o] pitch 68
    float* sB = (float*)(smem + 33792);  // 256 B
    const int blk = blockIdx.x - 8;      // 0..511
    const int bb = blk >> 6;
    const int n0 = (blk & 63) * 64;
    const float* pb = points + (size_t)bb * ND * NPTS;
    for (int f = t; f < 4096; f += 512) {
      int c = f >> 6, n = f & 63;
      sP[f] = pb[c * NPTS + n0 + n];
    }
    for (int f = t; f < 4096; f += 512) {
      int c = f >> 6, o = f & 63;
      sW[c * 68 + o] = W0[o * 67 + 3 + c];
    }
    if (t < 64) sB[t] = b0g[t];
    __syncthreads();
    if (t < 256) {
      const int nl = (t & 15) * 4;
      const int ol = (t >> 4) * 4;
      float acc[4][4];
#pragma unroll
      for (int i = 0; i < 4; ++i)
#pragma unroll
        for (int j = 0; j < 4; ++j) acc[i][j] = 0.f;
#pragma unroll 4
      for (int c = 0; c < 64; ++c) {
        float4 xv = *(const float4*)(sP + c * 64 + nl);
        float4 wv = *(const float4*)(sW + c * 68 + ol);
        float xa[4] = {xv.x, xv.y, xv.z, xv.w};
        float wa[4] = {wv.x, wv.y, wv.z, wv.w};
#pragma unroll
        for (int i = 0; i < 4; ++i)
#pragma unroll
          for (int j = 0; j < 4; ++j) acc[i][j] += xa[i] * wa[j];
      }
#pragma unroll
      for (int i = 0; i < 4; ++i) {
        ushort4 v;
        v.x = (unsigned short)f2bf(acc[i][0] + sB[ol + 0]);
        v.y = (unsigned short)f2bf(acc[i][1] + sB[ol + 1]);
        v.z = (unsigned short)f2bf(acc[i][2] + sB[ol + 2]);
        v.w = (unsigned short)f2bf(acc[i][3] + sB[ol + 3]);
        *(ushort4*)(P1 + ((size_t)(bb << 12) + n0 + nl + i) * 64 + ol) = v;
      }
    }
  }
}

// ------------------------------------------------------------------
// Ball query + layer-0 gather stats fused; materializes y0 (bf16).
// P1 read as bf16.
// ------------------------------------------------------------------
__global__ __launch_bounds__(256) void query_gstats_kernel(
    const float* __restrict__ xyz, const float* __restrict__ ws_newxyz,
    const unsigned short* __restrict__ P1, const float* __restrict__ W0,
    unsigned short* __restrict__ y0g, float* __restrict__ partials) {
  const int w = threadIdx.x >> 6;
  const int lane = threadIdx.x & 63;
  const int p = blockIdx.x * 4 + w;  // 8192 pairs
  const int b = p >> 10;
  __shared__ int sIdx[4][32];
  __shared__ float sWS[4][64];
  __shared__ float sWQ[4][64];
  const float* xb = xyz + (size_t)b * 3 * NPTS;
  const float cx = ws_newxyz[p * 3 + 0];
  const float cy = ws_newxyz[p * 3 + 1];
  const float cz = ws_newxyz[p * 3 + 2];
  const float ss = __fadd_rn(__fadd_rn(__fmul_rn(cx, cx), __fmul_rn(cy, cy)), __fmul_rn(cz, cz));
  const float r2 = (float)(0.4 * 0.4);
  int cnt = 0;
  for (int ci = 0; ci < 64 && cnt < 32; ++ci) {
    int n = ci * 64 + lane;
    float x = xb[n], y = xb[NPTS + n], z = xb[2 * NPTS + n];
    float dot = __fadd_rn(__fadd_rn(__fmul_rn(cx, x), __fmul_rn(cy, y)), __fmul_rn(cz, z));
    float dd = __fadd_rn(__fadd_rn(__fmul_rn(x, x), __fmul_rn(y, y)), __fmul_rn(z, z));
    float d = __fmul_rn(-2.0f, dot);
    d = __fadd_rn(d, ss);
    d = __fadd_rn(d, dd);
    d = fmaxf(d, 1e-12f);  // clip
    bool inc = (d <= r2);
    unsigned long long m = __ballot(inc);
    int slot = cnt + (int)__popcll(m & ((1ull << lane) - 1ull));
    if (inc && slot < 32) sIdx[w][slot] = n;
    cnt += (int)__popcll(m);
  }
  if (lane < 32) {
    int v;
    if (lane < cnt) v = sIdx[w][lane];
    else v = (cnt > 0) ? sIdx[w][0] : 0;
    sIdx[w][lane] = v;
  }
  const float wx = W0[lane * 67 + 0];
  const float wy = W0[lane * 67 + 1];
  const float wz = W0[lane * 67 + 2];
  float ssum = 0.f, ssq = 0.f;
  unsigned short* y0p = y0g + (size_t)p * 2048;
  for (int r = 0; r < 32; ++r) {
    const int n = sIdx[w][r];
    float P1v = bf2f(P1[((size_t)(b << 12) + n) * 64 + lane]);
    float dx = __fadd_rn(xb[n], -cx);
    float dy = __fadd_rn(xb[NPTS + n], -cy);
    float dz = __fadd_rn(xb[2 * NPTS + n], -cz);
    float y = P1v + (dx * wx + dy * wy + dz * wz);
    y0p[r * 64 + lane] = (unsigned short)f2bf(y);
    ssum += y;
    ssq += y * y;
  }
  sWS[w][lane] = ssum;
  sWQ[w][lane] = ssq;
  __syncthreads();
  const int t = threadIdx.x;
  if (t < 64) {
    float s1 = sWS[0][t] + sWS[1][t] + sWS[2][t] + sWS[3][t];
    float s2 = sWQ[0][t] + sWQ[1][t] + sWQ[2][t] + sWQ[3][t];
    partials[(size_t)blockIdx.x * 128 + t] = s1;
    partials[(size_t)blockIdx.x * 128 + 64 + t] = s2;
  }
}

// ------------------------------------------------------------------
// conv1 via MFMA bf16 — stages y0 flat (no gather), BN0+ReLU applied
// from LDS scale/shift; y1 stored bf16.
// ------------------------------------------------------------------
__global__ __launch_bounds__(256) void conv1_mfma_kernel(
    const unsigned short* __restrict__ y0, const float* __restrict__ W1,
    const float* __restrict__ b1, const float* __restrict__ scaleA,
    const float* __restrict__ shiftA, unsigned short* __restrict__ y1,
    float* __restrict__ partials) {
  __shared__ __align__(16) short sW1b[64 * 72];   // 9216 B
  __shared__ __align__(16) short sXb[128 * 72];   // 18432 B
  __shared__ float sScale[64], sShift[64], sBias[64];

  const int t = threadIdx.x;
  const int wv = t >> 6, lane = t & 63;
  const int quad = lane >> 4, l15 = lane & 15;
  const int pair0 = blockIdx.x * 4;

  if (t < 64) { sScale[t] = scaleA[t]; sShift[t] = shiftA[t]; sBias[t] = b1[t]; }
  for (int f = t; f < 4096; f += 256) sW1b[(f >> 6) * 72 + (f & 63)] = f2bf(W1[f]);
  __syncthreads();  // sScale/sShift visible before staging reads them

  const unsigned short* y0b = y0 + (size_t)pair0 * 2048;
  for (int f = t; f < 2048; f += 256) {
    ushort4 v4 = ((const ushort4*)y0b)[f];
    const int row = f >> 4, c4 = (f & 15) * 4;
    short4 o4;
    o4.x = f2bf(fmaxf(bf2f(v4.x) * sScale[c4 + 0] + sShift[c4 + 0], 0.f));
    o4.y = f2bf(fmaxf(bf2f(v4.y) * sScale[c4 + 1] + sShift[c4 + 1], 0.f));
    o4.z = f2bf(fmaxf(bf2f(v4.z) * sScale[c4 + 2] + sShift[c4 + 2], 0.f));
    o4.w = f2bf(fmaxf(bf2f(v4.w) * sScale[c4 + 3] + sShift[c4 + 3], 0.f));
    *(short4*)(sXb + row * 72 + c4) = o4;
  }
  __syncthreads();

  f32x4 acc[8];
#pragma unroll
  for (int i = 0; i < 8; ++i) acc[i] = (f32x4){0.f, 0.f, 0.f, 0.f};
#pragma unroll
  for (int kh = 0; kh < 2; ++kh) {
    const int kc = kh * 32 + quad * 8;
    bf16x8 A = *(const bf16x8*)(sW1b + (wv * 16 + l15) * 72 + kc);
#pragma unroll
    for (int ti = 0; ti < 8; ++ti) {
      bf16x8 B = *(const bf16x8*)(sXb + (ti * 16 + l15) * 72 + kc);
      acc[ti] = __builtin_amdgcn_mfma_f32_16x16x32_bf16(A, B, acc[ti], 0, 0, 0);
    }
  }

#pragma unroll
  for (int reg = 0; reg < 4; ++reg) {
    const int m = wv * 16 + quad * 4 + reg;
    const float bb = sBias[m];
    float v[8];
#pragma unroll
    for (int ti = 0; ti < 8; ++ti) {
      v[ti] = acc[ti][reg] + bb;
      y1[(size_t)(pair0 + (ti >> 1)) * 2048 + m * 32 + (ti & 1) * 16 + l15] =
          (unsigned short)f2bf(v[ti]);
    }
    float s1 = ((v[0] + v[1]) + (v[2] + v[3])) + ((v[4] + v[5]) + (v[6] + v[7]));
    float s2 = ((v[0] * v[0] + v[1] * v[1]) + (v[2] * v[2] + v[3] * v[3])) +
               ((v[4] * v[4] + v[5] * v[5]) + (v[6] * v[6] + v[7] * v[7]));
    DPP_RED16(s1, fadd_op)
    DPP_RED16(s2, fadd_op)
    if (l15 == 15) {
      partials[(size_t)blockIdx.x * 128 + m] = s1;
      partials[(size_t)blockIdx.x * 128 + 64 + m] = s2;
    }
  }
}

// ------------------------------------------------------------------
// conv2 via MFMA bf16 — y1 read as bf16; barrier after scale/shift
// staging.
// ------------------------------------------------------------------
__global__ __launch_bounds__(256) void conv2_mfma_kernel(
    const unsigned short* __restrict__ y1, const float* __restrict__ W2,
    const float* __restrict__ b2, const float* __restrict__ scaleA,
    const float* __restrict__ shiftA, float* __restrict__ pmaxT,
    float* __restrict__ pminT, float* __restrict__ partials) {
  __shared__ __align__(16) short sW2[128 * 72];  // 18432 B, [o][c] pitch 72
  __shared__ __align__(16) short sXb[128 * 72];  // 18432 B, 4 s x [n][c]
  __shared__ float sScale[64], sShift[64], sBias[128];

  const int t = threadIdx.x;
  const int pair0 = blockIdx.x * 4;
  const int lane = t & 63;
  const int wv = t >> 6;
  const int quad = lane >> 4;
  const int l15 = lane & 15;

  if (t < 64) { sScale[t] = scaleA[t]; sShift[t] = shiftA[t]; }
  if (t < 128) sBias[t] = b2[t];
  __syncthreads();  // sScale/sShift visible before staging reads them
  for (int f = t; f < 8192; f += 256) {
    int o = f >> 6, c = f & 63;
    sW2[o * 72 + c] = f2bf(W2[f]);
  }
  for (int f = t; f < 8192; f += 256) {
    int si = f >> 11;
    int rmd = f & 2047;
    int o = rmd >> 5, k = rmd & 31;
    float v = bf2f(y1[(size_t)(pair0 + si) * 2048 + rmd]);
    v = v * sScale[o] + sShift[o];
    v = fmaxf(v, 0.f);
    sXb[(si * 32 + k) * 72 + o] = f2bf(v);
  }
  __syncthreads();

  f32x4 acc[2][8];
#pragma unroll
  for (int i = 0; i < 2; ++i)
#pragma unroll
    for (int ti = 0; ti < 8; ++ti) acc[i][ti] = (f32x4){0.f, 0.f, 0.f, 0.f};
#pragma unroll
  for (int kh = 0; kh < 2; ++kh) {
    const int kc = kh * 32 + quad * 8;
    bf16x8 A0 = *(const bf16x8*)(sW2 + (wv * 32 + l15) * 72 + kc);
    bf16x8 A1 = *(const bf16x8*)(sW2 + (wv * 32 + 16 + l15) * 72 + kc);
#pragma unroll
    for (int ti = 0; ti < 8; ++ti) {
      bf16x8 B = *(const bf16x8*)(sXb + (ti * 16 + l15) * 72 + kc);
      acc[0][ti] = __builtin_amdgcn_mfma_f32_16x16x32_bf16(A0, B, acc[0][ti], 0, 0, 0);
      acc[1][ti] = __builtin_amdgcn_mfma_f32_16x16x32_bf16(A1, B, acc[1][ti], 0, 0, 0);
    }
  }

#pragma unroll
  for (int i = 0; i < 2; ++i) {
#pragma unroll
    for (int reg = 0; reg < 4; ++reg) {
      const int m = wv * 32 + i * 16 + quad * 4 + reg;
      const float bb = sBias[m];
      float v[8];
#pragma unroll
      for (int ti = 0; ti < 8; ++ti) v[ti] = acc[i][ti][reg] + bb;
      float s1 = ((v[0] + v[1]) + (v[2] + v[3])) + ((v[4] + v[5]) + (v[6] + v[7]));
      float s2 = ((v[0] * v[0] + v[1] * v[1]) + (v[2] * v[2] + v[3] * v[3])) +
                 ((v[4] * v[4] + v[5] * v[5]) + (v[6] * v[6] + v[7] * v[7]));
      DPP_RED16(s1, fadd_op)
      DPP_RED16(s2, fadd_op)
      if (l15 == 15) {
        partials[(size_t)blockIdx.x * 256 + m] = s1;
        partials[(size_t)blockIdx.x * 256 + 128 + m] = s2;
      }
#pragma unroll
      for (int si = 0; si < 4; ++si) {
        float mx = fmaxf(v[2 * si], v[2 * si + 1]);
        float mn = fminf(v[2 * si], v[2 * si + 1]);
        DPP_RED16(mx, fmaxf)
        DPP_RED16(mn, fminf)
        if (l15 == 15) {
          pmaxT[(size_t)m * 8192 + pair0 + si] = mx;
          pminT[(size_t)m * 8192 + pair0 + si] = mn;
        }
      }
    }
  }
}

// one block per channel: f64 reduce -> fused scale/shift for next layer
template <int COUT>
__global__ __launch_bounds__(256) void stats_kernel(const float* __restrict__ partials,
                                                    int nblocks,
                                                    const float* __restrict__ gA,
                                                    const float* __restrict__ btA,
                                                    float* __restrict__ scaleA,
                                                    float* __restrict__ shiftA) {
  const int o = blockIdx.x;
  const int t = threadIdx.x;
  double s1 = 0.0, s2 = 0.0;
  for (int blk = t; blk < nblocks; blk += 256) {
    s1 += (double)partials[(size_t)blk * (COUT * 2) + o];
    s2 += (double)partials[(size_t)blk * (COUT * 2) + COUT + o];
  }
  __shared__ double r1[256], r2[256];
  r1[t] = s1; r2[t] = s2;
  __syncthreads();
  for (int st = 128; st > 0; st >>= 1) {
    if (t < st) { r1[t] += r1[t + st]; r2[t] += r2[t + st]; }
    __syncthreads();
  }
  if (t == 0) {
    const double Nr = 262144.0;  // B*K*S
    double mean = r1[0] / Nr;
    double var = r2[0] / Nr - mean * mean;
    double rstd = 1.0 / sqrt(var + 1e-5);
    double sc = rstd * (double)gA[o];
    scaleA[o] = (float)sc;
    shiftA[o] = (float)((double)btA[o] - mean * sc);
  }
}

// layer-2 stats + final normalize fused: one block per channel (128).
__global__ __launch_bounds__(256) void stats_final_kernel(
    const float* __restrict__ partials, int nblocks,
    const float* __restrict__ pmaxT, const float* __restrict__ pminT,
    const float* __restrict__ gA, const float* __restrict__ btA,
    float* __restrict__ out) {
  const int o = blockIdx.x;
  const int t = threadIdx.x;
  double s1 = 0.0, s2 = 0.0;
  for (int blk = t; blk < nblocks; blk += 256) {
    s1 += (double)partials[(size_t)blk * 256 + o];
    s2 += (double)partials[(size_t)blk * 256 + 128 + o];
  }
  __shared__ double r1[256], r2[256];
  __shared__ float sMean, sRstd;
  r1[t] = s1; r2[t] = s2;
  __syncthreads();
  for (int st = 128; st > 0; st >>= 1) {
    if (t < st) { r1[t] += r1[t + st]; r2[t] += r2[t + st]; }
    __syncthreads();
  }
  if (t == 0) {
    const double Nr = 262144.0;
    double mean = r1[0] / Nr;
    double var = r2[0] / Nr - mean * mean;
    sMean = (float)mean;
    sRstd = (float)(1.0 / sqrt(var + 1e-5));
  }
  __syncthreads();
  const float mn = sMean, rs = sRstd, gg = gA[o], bb = btA[o];
  const float slope = rs * gg;
  const float* src = (slope >= 0.f) ? pmaxT : pminT;
  for (int i = t; i < NB * NS; i += 256) {
    int b = i >> 10;
    int s = i & 1023;
    float v = src[(size_t)o * 8192 + i];
    float t1 = (v - mn) * rs;
    float t2 = t1 * gg + bb;
    out[(size_t)b * (128 * NS) + o * NS + s] = fmaxf(t2, 0.f);
  }
}

extern "C" void kernel_launch(void* const* d_in, const int* in_sizes, int n_in,
                              void* d_out, int out_size, void* d_ws, size_t ws_size,
                              hipStream_t stream) {
  (void)in_sizes; (void)n_in; (void)out_size; (void)ws_size;
  const float* xyz = (const float*)d_in[0];
  const float* points = (const float*)d_in[1];
  const float* W0 = (const float*)d_in[2];
  const float* b0 = (const float*)d_in[3];
  const float* g0 = (const float*)d_in[4];
  const float* bt0 = (const float*)d_in[5];
  const float* W1 = (const float*)d_in[6];
  const float* b1 = (const float*)d_in[7];
  const float* g1 = (const float*)d_in[8];
  const float* bt1 = (const float*)d_in[9];
  const float* W2 = (const float*)d_in[10];
  const float* b2 = (const float*)d_in[11];
  const float* g2 = (const float*)d_in[12];
  const float* bt2 = (const float*)d_in[13];
  float* out = (float*)d_out;

  float* ws = (float*)d_ws;
  size_t off = 0;
  float* newxyz = ws + off;  off += (size_t)NB * NS * 3;
  unsigned short* P1 = (unsigned short*)(ws + off);
  off += (size_t)NB * NPTS * 64;  // alloc as before; bf16 uses half
  unsigned short* y0 = (unsigned short*)(ws + off);
  off += (size_t)8192 * 1024;  // 8192 pairs x 2048 bf16 = 32MB
  unsigned short* y1 = (unsigned short*)(ws + off);
  off += (size_t)NB * NS * 1024;  // 8192 x 2048 bf16 = 32MB
  float* partials = ws + off; off += (size_t)8192 * 256;
  float* scaleA = ws + off;  off += 128;
  float* shiftA = ws + off;  off += 128;
  float* pmaxT = ws + off;   off += (size_t)128 * NB * NS;
  float* pminT = ws + off;   off += (size_t)128 * NB * NS;

  // blocks 0-7: fps (8 CUs); blocks 8-519: pgemm hidden on idle CUs
  fps_pgemm_kernel<<<520, 512, 0, stream>>>(xyz, out, newxyz, points, W0, b0, P1);
  query_gstats_kernel<<<2048, 256, 0, stream>>>(xyz, newxyz, P1, W0, y0, partials);
  stats_kernel<64><<<64, 256, 0, stream>>>(partials, 2048, g0, bt0, scaleA, shiftA);
  conv1_mfma_kernel<<<2048, 256, 0, stream>>>(y0, W1, b1, scaleA, shiftA, y1,
                                              partials);
  stats_kernel<64><<<64, 256, 0, stream>>>(partials, 2048, g1, bt1, scaleA, shiftA);
  conv2_mfma_kernel<<<2048, 256, 0, stream>>>(y1, W2, b2, scaleA, shiftA,
                                              pmaxT, pminT, partials);
  stats_final_kernel<<<128, 256, 0, stream>>>(partials, 2048, pmaxT, pminT,
                                              g2, bt2, out + NB * NS * 3);
}